// Round 1
// baseline (234.387 us; speedup 1.0000x reference)
//
#include <hip/hip_runtime.h>
#include <math.h>

// RPNLayer: logits = x(32768,1024) @ W(1024,16) + b; per-anchor (8) 2-class
// log-softmax CE over valid (label != -1) anchors; argmax + candidate mask.
// Memory-bound: 128 MiB input read dominates -> ~21 us floor at 6.3 TB/s.
//
// Layout of d_out (float32, 524289 elems):
//   [0]                      loss scalar
//   [1 .. 262144]            predict_label (0.0 / 1.0)
//   [262145 .. 524288]       candidate_mask (0.0 / 1.0)

#define ROWS 64        // rows per block (= lanes per wave)
#define NWAVE 4        // waves per block; each owns a 256-wide K slice
#define DWAVE 256      // K elems per wave
#define CHUNK 32       // K elems staged per iteration
#define XPAD 33        // LDS row stride (floats): banks (lane+d)%32 -> 2-way (free)

__global__ __launch_bounds__(256, 3)
void rpn_main(const float* __restrict__ x, const float* __restrict__ W,
              const float* __restrict__ b, const int* __restrict__ lab,
              float* __restrict__ out, float* __restrict__ ws)
{
    __shared__ float xs[NWAVE][ROWS * XPAD];        // 4*64*33*4  = 33792 B
    __shared__ float red[ROWS][NWAVE * 16 + 4];     // 64*68*4    = 17408 B

    const int tid  = threadIdx.x;
    const int wave = tid >> 6;
    const int lane = tid & 63;
    const int row0 = blockIdx.x * ROWS;

    // wave index is wave-uniform; readfirstlane lets the compiler prove it,
    // so all W accesses below become s_load (scalar pipe, SGPR operands).
    const int uwave = __builtin_amdgcn_readfirstlane(wave);
    const float* __restrict__ Wp = W + (size_t)uwave * DWAVE * 16;

    const float* __restrict__ gbase = x + (size_t)row0 * 1024 + (size_t)wave * DWAVE;

    float acc[16];
#pragma unroll
    for (int c = 0; c < 16; ++c) acc[c] = 0.f;

    for (int ch = 0; ch < DWAVE / CHUNK; ++ch) {
        // ---- stage 64 rows x 32 K-elems: coalesced float4 global loads ----
        const float* gsrc = gbase + ch * CHUNK;
#pragma unroll
        for (int j = 0; j < 8; ++j) {
            int fl = j * 64 + lane;        // 512 float4s, row-major -> coalesced
            int r  = fl >> 3;
            int c4 = fl & 7;
            float4 v = *(const float4*)(gsrc + (size_t)r * 1024 + c4 * 4);
            float* dst = &xs[wave][r * XPAD + c4 * 4];
            dst[0] = v.x; dst[1] = v.y; dst[2] = v.z; dst[3] = v.w;
        }
        __syncthreads();

        // ---- each lane = one row: 32 x 16 FMAs, W from SGPRs ----
        const float* __restrict__ Wc = Wp + ch * CHUNK * 16;
        const float* xrow = &xs[wave][lane * XPAD];
#pragma unroll 4
        for (int dd = 0; dd < CHUNK; ++dd) {
            float xv = xrow[dd];
#pragma unroll
            for (int c = 0; c < 16; ++c)
                acc[c] = fmaf(xv, Wc[dd * 16 + c], acc[c]);
        }
        __syncthreads();
    }

    // ---- cross-wave reduction of K-slice partials ----
#pragma unroll
    for (int c = 0; c < 16; c += 4) {
        float4 v = make_float4(acc[c], acc[c + 1], acc[c + 2], acc[c + 3]);
        *(float4*)&red[lane][wave * 16 + c] = v;
    }
    __syncthreads();

    if (tid < 64) {
        const int row = row0 + tid;
        float L[16];
#pragma unroll
        for (int c = 0; c < 16; ++c)
            L[c] = red[tid][c] + red[tid][16 + c] + red[tid][32 + c] + red[tid][48 + c]
                 + b[c];

        const int*  labp  = lab + (size_t)row * 8;
        float*      predp = out + 1 + (size_t)row * 8;
        float*      maskp = out + 1 + 262144 + (size_t)row * 8;

        float lsum = 0.f, lcnt = 0.f;
#pragma unroll
        for (int a = 0; a < 8; ++a) {
            float l0 = L[2 * a], l1 = L[2 * a + 1];
            int   lb = labp[a];
            int   pred  = (l1 > l0) ? 1 : 0;           // tie -> 0, matches argmax
            int   valid = (lb != -1);
            float m   = fmaxf(l0, l1);
            float lse = m + logf(expf(l0 - m) + expf(l1 - m));
            float nll = lse - ((lb == 1) ? l1 : l0);   // label = max(lb,0)
            if (valid) { lsum += nll; lcnt += 1.f; }
            predp[a] = (float)pred;
            maskp[a] = (pred && valid) ? 1.f : 0.f;
        }

        // wave-level reduce (wave 0 only is active here)
#pragma unroll
        for (int off = 32; off > 0; off >>= 1) {
            lsum += __shfl_down(lsum, off);
            lcnt += __shfl_down(lcnt, off);
        }
        if (tid == 0) {
            atomicAdd(&ws[0], lsum);
            atomicAdd(&ws[1], lcnt);
        }
    }
}

__global__ void rpn_final(const float* __restrict__ ws, float* __restrict__ out)
{
    out[0] = ws[0] / fmaxf(ws[1], 1.f);
}

extern "C" void kernel_launch(void* const* d_in, const int* in_sizes, int n_in,
                              void* d_out, int out_size, void* d_ws, size_t ws_size,
                              hipStream_t stream)
{
    const float* x   = (const float*)d_in[0];   // (64,512,1024) f32
    const float* W   = (const float*)d_in[1];   // (1024,16) f32
    const float* b   = (const float*)d_in[2];   // (16,) f32
    const int*   lab = (const int*)d_in[3];     // (64,512,8) i32 in {-1,0,1}
    float* out = (float*)d_out;
    float* ws  = (float*)d_ws;

    hipMemsetAsync(ws, 0, 2 * sizeof(float), stream);
    rpn_main<<<dim3(512), dim3(256), 0, stream>>>(x, W, b, lab, out, ws);
    rpn_final<<<dim3(1), dim3(1), 0, stream>>>(ws, out);
}

// Round 2
// 217.526 us; speedup vs baseline: 1.0775x; 1.0775x over previous
//
#include <hip/hip_runtime.h>
#include <math.h>

// RPNLayer: logits = x(32768,1024) @ W(1024,16) + b; per-anchor (8) 2-class
// log-softmax CE over valid anchors; argmax + candidate mask.
//
// R2 structure: 32 rows/block, 1024 blocks (4 blocks/CU -> 16 waves/CU).
// Wave w owns K-slice [w*256, (w+1)*256). Lane = (row r = lane&31,
// channel-half h = lane>>5, 8 channels each). Both x chunk AND W chunk are
// staged in LDS; W reads are 2-address near-broadcast ds_read_b128 (fixes
// R1's W reload storm that left the kernel 90% stalled at 8.5% VALUBusy).
//
// d_out (float32): [0] loss | [1..262144] predict | [262145..524288] mask

#define ROWS   32
#define NW     4
#define KSLICE 256
#define CHUNK  32
#define XSTR   36   // floats; 144 B row stride: 16B-aligned, bank-spread

__global__ __launch_bounds__(256, 4)
void rpn_main(const float* __restrict__ x, const float* __restrict__ W,
              const float* __restrict__ b, const int* __restrict__ lab,
              float* __restrict__ out, float* __restrict__ ws)
{
    __shared__ float xs[NW * ROWS * XSTR];   // 4608 floats = 18432 B
    __shared__ float wch[NW * CHUNK * 16];   // 2048 floats =  8192 B
    float* red = xs;                         // aliased: lifetimes disjoint

    const int tid  = threadIdx.x;
    const int wave = tid >> 6;
    const int lane = tid & 63;
    const int r    = lane & 31;
    const int h    = lane >> 5;              // channel half: 0 -> c0..7, 1 -> c8..15
    const int row0 = blockIdx.x * ROWS;

    float* xslab = xs + wave * (ROWS * XSTR);
    const float* gx = x + (size_t)row0 * 1024 + wave * KSLICE;

    float acc[8];
#pragma unroll
    for (int c = 0; c < 8; ++c) acc[c] = 0.f;

    for (int ch = 0; ch < KSLICE / CHUNK; ++ch) {
        // ---- stage x: 32 rows x 32 floats per wave slice, coalesced f4 ----
        const float* gsrc = gx + ch * CHUNK;
#pragma unroll
        for (int j = 0; j < 4; ++j) {
            int fl = j * 64 + lane;          // 256 float4s
            int rr = fl >> 3;
            int c4 = fl & 7;
            float4 v = *(const float4*)(gsrc + (size_t)rr * 1024 + c4 * 4);
            *(float4*)(xslab + rr * XSTR + c4 * 4) = v;
        }
        // ---- stage W chunk: 128 rows x 16 ch = 8 KB, 2 float4/thread ----
        // wch flat e maps to global W flat: e + (e>>9)*3584 + ch*512
#pragma unroll
        for (int j = 0; j < 2; ++j) {
            int e = (tid + 256 * j) * 4;
            float4 wv = *(const float4*)(W + e + (e >> 9) * 3584 + ch * 512);
            *(float4*)(wch + e) = wv;
        }
        __syncthreads();

        // ---- compute: lane owns (row r, channels h*8..h*8+7) ----
        const float* xrow = xslab + r * XSTR;
        const float* wp   = wch + wave * (CHUNK * 16) + h * 8;
#pragma unroll
        for (int t4 = 0; t4 < 8; ++t4) {
            float4 xq = *(const float4*)(xrow + t4 * 4);
#pragma unroll
            for (int i = 0; i < 4; ++i) {
                int dd = t4 * 4 + i;
                float xv = (&xq.x)[i];
                float4 w0 = *(const float4*)(wp + dd * 16);
                float4 w1 = *(const float4*)(wp + dd * 16 + 4);
                acc[0] = fmaf(xv, w0.x, acc[0]);
                acc[1] = fmaf(xv, w0.y, acc[1]);
                acc[2] = fmaf(xv, w0.z, acc[2]);
                acc[3] = fmaf(xv, w0.w, acc[3]);
                acc[4] = fmaf(xv, w1.x, acc[4]);
                acc[5] = fmaf(xv, w1.y, acc[5]);
                acc[6] = fmaf(xv, w1.z, acc[6]);
                acc[7] = fmaf(xv, w1.w, acc[7]);
            }
        }
        __syncthreads();
    }

    // ---- write K-slice partials (red aliases xs; all waves past barrier) ----
    {
        float* rp = red + r * 68 + wave * 16 + h * 8;
        *(float4*)(rp)     = make_float4(acc[0], acc[1], acc[2], acc[3]);
        *(float4*)(rp + 4) = make_float4(acc[4], acc[5], acc[6], acc[7]);
    }
    __syncthreads();

    // ---- epilogue: one thread per row ----
    if (tid < ROWS) {
        const int row = row0 + tid;
        float L[16];
#pragma unroll
        for (int c = 0; c < 16; ++c)
            L[c] = red[tid * 68 + c] + red[tid * 68 + 16 + c]
                 + red[tid * 68 + 32 + c] + red[tid * 68 + 48 + c] + b[c];

        const int* labp  = lab + (size_t)row * 8;
        float*     predp = out + 1 + (size_t)row * 8;
        float*     maskp = out + 1 + 262144 + (size_t)row * 8;

        float lsum = 0.f, lcnt = 0.f;
#pragma unroll
        for (int a = 0; a < 8; ++a) {
            float l0 = L[2 * a], l1 = L[2 * a + 1];
            int   lb = labp[a];
            int   pred  = (l1 > l0) ? 1 : 0;          // strict: tie -> class 0
            int   valid = (lb != -1);
            float m   = fmaxf(l0, l1);
            float lse = m + logf(expf(l0 - m) + expf(l1 - m));
            float nll = lse - ((lb == 1) ? l1 : l0);
            if (valid) { lsum += nll; lcnt += 1.f; }
            predp[a] = (float)pred;
            maskp[a] = (pred && valid) ? 1.f : 0.f;
        }

        // reduce across the 32 active lanes (stay within width 32)
#pragma unroll
        for (int off = 16; off > 0; off >>= 1) {
            lsum += __shfl_down(lsum, off, 32);
            lcnt += __shfl_down(lcnt, off, 32);
        }
        if (tid == 0) {
            atomicAdd(&ws[0], lsum);
            atomicAdd(&ws[1], lcnt);
        }
    }
}

__global__ void rpn_final(const float* __restrict__ ws, float* __restrict__ out)
{
    out[0] = ws[0] / fmaxf(ws[1], 1.f);
}

extern "C" void kernel_launch(void* const* d_in, const int* in_sizes, int n_in,
                              void* d_out, int out_size, void* d_ws, size_t ws_size,
                              hipStream_t stream)
{
    const float* x   = (const float*)d_in[0];   // (64,512,1024) f32
    const float* W   = (const float*)d_in[1];   // (1024,16) f32
    const float* b   = (const float*)d_in[2];   // (16,) f32
    const int*   lab = (const int*)d_in[3];     // (64,512,8) i32 in {-1,0,1}
    float* out = (float*)d_out;
    float* ws  = (float*)d_ws;

    hipMemsetAsync(ws, 0, 2 * sizeof(float), stream);
    rpn_main<<<dim3(1024), dim3(256), 0, stream>>>(x, W, b, lab, out, ws);
    rpn_final<<<dim3(1), dim3(1), 0, stream>>>(ws, out);
}